// Round 3
// baseline (377.542 us; speedup 1.0000x reference)
//
#include <hip/hip_runtime.h>
#include <stdint.h>

#define BH 32
#define LSEQ 4096
#define DDIM 128
#define CHUNKS 16
#define CHUNK_ROWS 256
#define STATE_SZ (DDIM*DDIM + DDIM)   // 16512 floats per (bh, chunk), [d][e] then Z[d]

typedef __attribute__((ext_vector_type(8))) short bf16x8;
typedef __attribute__((ext_vector_type(4))) float f32x4;

__device__ inline uint16_t f2bf(float f) {
    uint32_t x = __builtin_bit_cast(uint32_t, f);
    x += 0x7fffu + ((x >> 16) & 1u);
    return (uint16_t)(x >> 16);
}
__device__ inline uint32_t pack2(float a, float b) {
    return (uint32_t)f2bf(a) | ((uint32_t)f2bf(b) << 16);
}
// phi(x) = clip(elu(x*s+b)+1, 0, 10)
__device__ inline float phi_f(float x, float s, float b) {
    float y = fmaf(x, s, b);
    float pos = fminf(y + 1.0f, 10.0f);
    float neg = __expf(y);
    return (y > 0.0f) ? pos : neg;
}
// LDS-only barrier drain: keeps global prefetch loads in flight across barriers.
__device__ inline void bar_lgkm() {
    asm volatile("s_waitcnt lgkmcnt(0)\n\ts_barrier" ::: "memory");
}

// =====================================================================
// P1: per-chunk state totals  S_c = phi_K_c^T @ V_c  (K=256), Z_c
// LDS: pk bufs 2x16KB @0, vT bufs 2x16KB @32768, Zpart @65536 (2KB)
#define SMEM1 67584
__global__ __launch_bounds__(512, 4) void la_state(
    const float* __restrict__ K, const float* __restrict__ V,
    const float* __restrict__ scale, const float* __restrict__ bias,
    float* __restrict__ states)
{
    extern __shared__ char smem[];
    const int tid  = threadIdx.x;
    const int bh   = blockIdx.x >> 4;
    const int ch   = blockIdx.x & 15;
    const int h    = bh & 15;
    const int lane = tid & 63;
    const int wid  = tid >> 6;
    const int i15  = lane & 15;
    const int q4   = lane >> 4;
    const size_t base = (size_t)bh * LSEQ * DDIM;
    const int row0 = ch * CHUNK_ROWS;

    const int d  = tid & 127;
    const int rg = tid >> 7;
    const float sk = scale[h*DDIM + d];
    const float bk = bias [h*DDIM + d];

    f32x4 accS[8];
    #pragma unroll
    for (int mt = 0; mt < 8; ++mt) accS[mt] = (f32x4){0.f,0.f,0.f,0.f};
    float zacc = 0.f;

    float kreg[16], vreg[16];
    auto load_kv = [&](int g) {
        const float* Kc = K + base + (size_t)(row0 + 64*g + 16*rg)*DDIM + d;
        const float* Vc = V + base + (size_t)(row0 + 64*g + 16*rg)*DDIM + d;
        #pragma unroll
        for (int j = 0; j < 16; ++j) {
            kreg[j] = Kc[(size_t)j*DDIM];
            vreg[j] = Vc[(size_t)j*DDIM];
        }
    };
    auto stage = [&](int b) {
        uint32_t wk[8], wv8[8];
        #pragma unroll
        for (int j = 0; j < 8; ++j) {
            float p0 = phi_f(kreg[2*j],   sk, bk);
            float p1 = phi_f(kreg[2*j+1], sk, bk);
            zacc += p0 + p1;
            wk[j]  = pack2(p0, p1);
            wv8[j] = pack2(vreg[2*j], vreg[2*j+1]);
        }
        char* pkb = smem + b*16384;
        char* vtb = smem + 32768 + b*16384;
        const uint32_t lin = (uint32_t)(d*128 + 32*rg);
        const uint32_t swz = (uint32_t)((d & 7) << 4);
        *(uint4*)(pkb + ((lin     ) ^ swz)) = ((const uint4*)wk)[0];
        *(uint4*)(pkb + ((lin + 16) ^ swz)) = ((const uint4*)wk)[1];
        *(uint4*)(vtb + ((lin     ) ^ swz)) = ((const uint4*)wv8)[0];
        *(uint4*)(vtb + ((lin + 16) ^ swz)) = ((const uint4*)wv8)[1];
    };

    load_kv(0);
    stage(0);
    load_kv(1);
    bar_lgkm();

    #pragma unroll
    for (int g = 0; g < 4; ++g) {
        if (g < 3) stage((g+1)&1);
        if (g < 2) load_kv(g+2);
        const char* pkb = smem + (g&1)*16384;
        const char* vtb = smem + 32768 + (g&1)*16384;
        const uint32_t swz = (uint32_t)((i15 & 7) << 4);
        #pragma unroll
        for (int ksl = 0; ksl < 2; ++ksl) {
            bf16x8 bv = *(const bf16x8*)(vtb + (((uint32_t)((16*wid+i15)*128 + 64*ksl + 16*q4)) ^ swz));
            #pragma unroll
            for (int mt = 0; mt < 8; ++mt) {
                bf16x8 av = *(const bf16x8*)(pkb + (((uint32_t)((16*mt+i15)*128 + 64*ksl + 16*q4)) ^ swz));
                accS[mt] = __builtin_amdgcn_mfma_f32_16x16x32_bf16(av, bv, accS[mt], 0, 0, 0);
            }
        }
        bar_lgkm();
    }

    float* Zpart = (float*)(smem + 65536);
    Zpart[rg*128 + d] = zacc;
    float* stb = states + (size_t)(bh*CHUNKS + ch)*STATE_SZ;
    #pragma unroll
    for (int mt = 0; mt < 8; ++mt)
        #pragma unroll
        for (int r = 0; r < 4; ++r)
            stb[(size_t)(16*mt + 4*q4 + r)*DDIM + 16*wid + i15] = accS[mt][r];
    bar_lgkm();
    if (tid < 128)
        stb[DDIM*DDIM + tid] = Zpart[tid] + Zpart[128+tid] + Zpart[256+tid] + Zpart[384+tid];
}

// =====================================================================
// Prefix: in-place exclusive prefix over the 16 chunk states, 1 chain/thread.
__global__ void la_prefix(float* __restrict__ states) {
    const int bh  = blockIdx.y;
    const int idx = blockIdx.x * 128 + threadIdx.x;   // 129*128 = 16512 exact
    float* p = states + (size_t)bh * CHUNKS * STATE_SZ + idx;
    float run = 0.f;
    #pragma unroll
    for (int c = 0; c < CHUNKS; ++c) {
        float v = p[(size_t)c * STATE_SZ];
        p[(size_t)c * STATE_SZ] = run;
        run += v;
    }
}

// =====================================================================
// P2: out = (phi_Q @ S0 + blockcausal(phi_Q @ phi_K^T) @ V) / den
// Wave w owns q-tiles a=w and a=15-w (16 rows each) -> balanced causal work.
// kv granules of 32 rows, double-buffered. 2 wg/CU (LDS 70KB, VGPR<=128).
// LDS map:
//   [0,32768)       S0T [e=128][d=128] bf16 swz; A-scratch overlays after term1
//                   (per wave: wid*2560 + tile*1280, [16 q][40 r] bf16)
//   [32768,49152)   pk bufs 2 x [32 r][128 d] bf16 swz (8KB each)
//   [49152,69632)   vT bufs 2 x [128 e][40 r] bf16 pad (10KB each)
//   [69632,70656)   sbL: scale[128], bias[128] f32
//   [70656,71680)   denl [8 waves][32] f32
#define SMEM2 71680
__global__ __launch_bounds__(512, 4) void la_fwd(
    const float* __restrict__ Q, const float* __restrict__ K,
    const float* __restrict__ V, const float* __restrict__ scale,
    const float* __restrict__ bias, const float* __restrict__ states,
    float* __restrict__ out)
{
    extern __shared__ char smem[];
    char* S0T  = smem;
    char* pkB  = smem + 32768;
    char* vtB  = smem + 49152;
    float* sbL  = (float*)(smem + 69632);
    float* denl = (float*)(smem + 70656);

    const int tid  = threadIdx.x;
    const int bh   = blockIdx.x >> 4;
    const int ch   = blockIdx.x & 15;
    const int h    = bh & 15;
    const int lane = tid & 63;
    const int wid  = tid >> 6;
    const int i15  = lane & 15;
    const int q4   = lane >> 4;
    const size_t base = (size_t)bh * LSEQ * DDIM;
    const int row0 = ch * CHUNK_ROWS;
    const float* stb = states + (size_t)(bh*CHUNKS + ch)*STATE_SZ;

    // kv staging assignments (32-row granule)
    const int krow = tid >> 4;            // 0..31
    const int kc8  = (tid & 15) * 8;      // K col segment (8 wide)
    const int ve   = tid & 127;           // vT row (e)
    const int vrg  = tid >> 7;            // 0..3 -> r rows 8vrg..8vrg+7

    // q-tile ownership: balanced
    const int qa0 = wid, qa1 = 15 - wid;
    const int jmax0 = qa0 >> 1, jmax1 = qa1 >> 1;

    float4 kq[2];
    float  vr[8];
    auto load_kv = [&](int g) {
        const float* Kr = K + base + (size_t)(row0 + 32*g + krow)*DDIM + kc8;
        kq[0] = *(const float4*)(Kr);
        kq[1] = *(const float4*)(Kr + 4);
        const float* Vc = V + base + (size_t)(row0 + 32*g + 8*vrg)*DDIM + ve;
        #pragma unroll
        for (int j = 0; j < 8; ++j) vr[j] = Vc[(size_t)j*DDIM];
    };
    auto stage_kv = [&](int b) {
        float4 s0 = *(const float4*)&sbL[kc8];
        float4 s1 = *(const float4*)&sbL[kc8 + 4];
        float4 b0 = *(const float4*)&sbL[128 + kc8];
        float4 b1 = *(const float4*)&sbL[128 + kc8 + 4];
        uint32_t wk[4];
        wk[0] = pack2(phi_f(kq[0].x, s0.x, b0.x), phi_f(kq[0].y, s0.y, b0.y));
        wk[1] = pack2(phi_f(kq[0].z, s0.z, b0.z), phi_f(kq[0].w, s0.w, b0.w));
        wk[2] = pack2(phi_f(kq[1].x, s1.x, b1.x), phi_f(kq[1].y, s1.y, b1.y));
        wk[3] = pack2(phi_f(kq[1].z, s1.z, b1.z), phi_f(kq[1].w, s1.w, b1.w));
        const uint32_t lin = (uint32_t)(krow*256 + kc8*2);
        const uint32_t swz = (uint32_t)((krow & 7) << 4);
        *(uint4*)(pkB + b*8192 + (lin ^ swz)) = *(const uint4*)wk;
        uint32_t wv8[4];
        #pragma unroll
        for (int j = 0; j < 4; ++j) wv8[j] = pack2(vr[2*j], vr[2*j+1]);
        *(uint4*)(vtB + b*10240 + (uint32_t)(ve*80 + vrg*16)) = *(const uint4*)wv8;
    };

    load_kv(0);   // issue earliest

    // ---- stage scale/bias row into LDS
    if (tid < 256) sbL[tid] = (tid < 128) ? scale[h*DDIM + tid] : bias[h*DDIM + tid - 128];

    // ---- stage S0T [e][d] bf16 (2 passes of 16 d's to cap registers)
    {
        const int se  = tid & 127;
        const int sdg = tid >> 7;            // d range 32sdg..32sdg+31
        const uint32_t swz = (uint32_t)((se & 7) << 4);
        #pragma unroll
        for (int pass = 0; pass < 2; ++pass) {
            float sv[16];
            const float* sp = stb + (size_t)(32*sdg + 16*pass)*DDIM + se;
            #pragma unroll
            for (int k2 = 0; k2 < 16; ++k2) sv[k2] = sp[(size_t)k2*DDIM];
            uint32_t wbuf[8];
            #pragma unroll
            for (int k2 = 0; k2 < 8; ++k2) wbuf[k2] = pack2(sv[2*k2], sv[2*k2+1]);
            const uint32_t linb = (uint32_t)(se*256 + (32*sdg + 16*pass)*2);
            *(uint4*)(S0T + ((linb     ) ^ swz)) = ((const uint4*)wbuf)[0];
            *(uint4*)(S0T + ((linb + 16) ^ swz)) = ((const uint4*)wbuf)[1];
        }
    }

    // ---- phi_Q fragments in registers + den0 = phi_q . Z0
    bf16x8 pq[2][4];
    float dden0 = 0.f, dden1 = 0.f;
    #pragma unroll
    for (int ks = 0; ks < 4; ++ks) {
        const float* sp = scale + h*DDIM + 32*ks + 8*q4;
        const float* bp = bias  + h*DDIM + 32*ks + 8*q4;
        const float* zp = stb + DDIM*DDIM + 32*ks + 8*q4;
        float4 s0 = *(const float4*)sp, s1 = *(const float4*)(sp+4);
        float4 b0 = *(const float4*)bp, b1 = *(const float4*)(bp+4);
        float4 z0 = *(const float4*)zp, z1 = *(const float4*)(zp+4);
        #pragma unroll
        for (int tl = 0; tl < 2; ++tl) {
            const int a = tl ? qa1 : qa0;
            const float* qp = Q + base + (size_t)(row0 + 16*a + i15)*DDIM + 32*ks + 8*q4;
            float4 a0 = *(const float4*)qp, a1 = *(const float4*)(qp+4);
            float f0 = phi_f(a0.x, s0.x, b0.x), f1 = phi_f(a0.y, s0.y, b0.y);
            float f2 = phi_f(a0.z, s0.z, b0.z), f3 = phi_f(a0.w, s0.w, b0.w);
            float f4 = phi_f(a1.x, s1.x, b1.x), f5 = phi_f(a1.y, s1.y, b1.y);
            float f6 = phi_f(a1.z, s1.z, b1.z), f7 = phi_f(a1.w, s1.w, b1.w);
            float ds = f0*z0.x + f1*z0.y + f2*z0.z + f3*z0.w
                     + f4*z1.x + f5*z1.y + f6*z1.z + f7*z1.w;
            if (tl == 0) dden0 += ds; else dden1 += ds;
            uint4 uu = { pack2(f0,f1), pack2(f2,f3), pack2(f4,f5), pack2(f6,f7) };
            pq[tl][ks] = __builtin_bit_cast(bf16x8, uu);
        }
    }

    stage_kv(0);
    load_kv(1);
    bar_lgkm();   // B0: S0T + sbL + kv g0 visible

    // ---- term1: acc = phi_q @ S0
    f32x4 acc[2][8];
    #pragma unroll
    for (int tl = 0; tl < 2; ++tl)
        #pragma unroll
        for (int et = 0; et < 8; ++et) acc[tl][et] = (f32x4){0.f,0.f,0.f,0.f};
    {
        const uint32_t swz = (uint32_t)((i15 & 7) << 4);
        #pragma unroll
        for (int ks = 0; ks < 4; ++ks)
            #pragma unroll
            for (int et = 0; et < 8; ++et) {
                bf16x8 sb = *(const bf16x8*)(S0T + (((uint32_t)((16*et+i15)*256 + (32*ks + 8*q4)*2)) ^ swz));
                acc[0][et] = __builtin_amdgcn_mfma_f32_16x16x32_bf16(pq[0][ks], sb, acc[0][et], 0, 0, 0);
                acc[1][et] = __builtin_amdgcn_mfma_f32_16x16x32_bf16(pq[1][ks], sb, acc[1][et], 0, 0, 0);
            }
    }
    stage_kv(1);
    load_kv(2);
    bar_lgkm();   // B1: all term1 S0T reads done -> A-scratch may overwrite; kv g1 visible

    // ---- kv loop: 8 granules of 32 rows, double-buffered
    char* Ascr0 = S0T + wid*2560;
    char* Ascr1 = Ascr0 + 1280;
    const uint32_t swzf = (uint32_t)((i15 & 7) << 4);

    #pragma unroll
    for (int t = 0; t < 8; ++t) {
        if (t >= 1) {
            if (t + 1 <= 7) stage_kv((t+1)&1);
            if (t + 2 <= 7) load_kv(t+2);
        }
        const char* pk = pkB + (t&1)*8192;
        const char* vt = vtB + (t&1)*10240;
        #pragma unroll
        for (int tl = 0; tl < 2; ++tl) {
            const int jm = tl ? jmax1 : jmax0;
            if (t <= jm) {
                char* As = tl ? Ascr1 : Ascr0;
                f32x4 Aacc[2];
                Aacc[0] = (f32x4){0.f,0.f,0.f,0.f};
                Aacc[1] = (f32x4){0.f,0.f,0.f,0.f};
                #pragma unroll
                for (int ks = 0; ks < 4; ++ks) {
                    bf16x8 ak0 = *(const bf16x8*)(pk + (((uint32_t)((     i15)*256 + (32*ks + 8*q4)*2)) ^ swzf));
                    bf16x8 ak1 = *(const bf16x8*)(pk + (((uint32_t)((16 + i15)*256 + (32*ks + 8*q4)*2)) ^ swzf));
                    bf16x8 pqv = tl ? pq[1][ks] : pq[0][ks];
                    Aacc[0] = __builtin_amdgcn_mfma_f32_16x16x32_bf16(ak0, pqv, Aacc[0], 0, 0, 0);
                    Aacc[1] = __builtin_amdgcn_mfma_f32_16x16x32_bf16(ak1, pqv, Aacc[1], 0, 0, 0);
                }
                float dsum = Aacc[0][0]+Aacc[0][1]+Aacc[0][2]+Aacc[0][3]
                           + Aacc[1][0]+Aacc[1][1]+Aacc[1][2]+Aacc[1][3];
                if (tl == 0) dden0 += dsum; else dden1 += dsum;
                #pragma unroll
                for (int sub = 0; sub < 2; ++sub) {
                    uint2 o;
                    o.x = pack2(Aacc[sub][0], Aacc[sub][1]);
                    o.y = pack2(Aacc[sub][2], Aacc[sub][3]);
                    *(uint2*)(As + (uint32_t)((i15*40 + 16*sub + 4*q4)*2)) = o;
                }
                bf16x8 aq = *(const bf16x8*)(As + (uint32_t)((i15*40 + 8*q4)*2));
                #pragma unroll
                for (int et = 0; et < 8; ++et) {
                    bf16x8 bv = *(const bf16x8*)(vt + (uint32_t)((16*et+i15)*80 + q4*16));
                    acc[tl][et] = __builtin_amdgcn_mfma_f32_16x16x32_bf16(aq, bv, acc[tl][et], 0, 0, 0);
                }
            }
        }
        bar_lgkm();
    }

    // ---- den reduce (per wave, via shuffle + wave-private LDS) + store
    dden0 += __shfl_xor(dden0, 16, 64); dden0 += __shfl_xor(dden0, 32, 64);
    dden1 += __shfl_xor(dden1, 16, 64); dden1 += __shfl_xor(dden1, 32, 64);
    if (q4 == 0) {
        denl[wid*32 + i15]      = dden0;
        denl[wid*32 + 16 + i15] = dden1;
    }
    #pragma unroll
    for (int tl = 0; tl < 2; ++tl) {
        const int a = tl ? qa1 : qa0;
        float inv[4];
        #pragma unroll
        for (int r = 0; r < 4; ++r)
            inv[r] = 1.0f / fmaxf(denl[wid*32 + 16*tl + 4*q4 + r], 1e-6f);
        #pragma unroll
        for (int et = 0; et < 8; ++et)
            #pragma unroll
            for (int r = 0; r < 4; ++r)
                out[base + (size_t)(row0 + 16*a + 4*q4 + r)*DDIM + 16*et + i15] =
                    acc[tl][et][r] * inv[r];
    }
}

extern "C" void kernel_launch(void* const* d_in, const int* in_sizes, int n_in,
                              void* d_out, int out_size, void* d_ws, size_t ws_size,
                              hipStream_t stream) {
    const float* Q     = (const float*)d_in[0];
    const float* K     = (const float*)d_in[1];
    const float* V     = (const float*)d_in[2];
    const float* scale = (const float*)d_in[3];
    const float* bias  = (const float*)d_in[4];
    float* out    = (float*)d_out;
    float* states = (float*)d_ws;   // 32*16*16512*4 = 33.8 MB

    static bool s_attr = false;
    if (!s_attr) {
        hipFuncSetAttribute(reinterpret_cast<const void*>(la_state),
                            hipFuncAttributeMaxDynamicSharedMemorySize, SMEM1);
        hipFuncSetAttribute(reinterpret_cast<const void*>(la_fwd),
                            hipFuncAttributeMaxDynamicSharedMemorySize, SMEM2);
        s_attr = true;
    }

    hipLaunchKernelGGL(la_state, dim3(BH*CHUNKS), dim3(512), SMEM1, stream,
                       K, V, scale, bias, states);
    hipLaunchKernelGGL(la_prefix, dim3(129, BH), dim3(128), 0, stream, states);
    hipLaunchKernelGGL(la_fwd, dim3(BH*CHUNKS), dim3(512), SMEM2, stream,
                       Q, K, V, scale, bias, states, out);
}

// Round 4
// 284.751 us; speedup vs baseline: 1.3259x; 1.3259x over previous
//
#include <hip/hip_runtime.h>
#include <stdint.h>

#define BH 32
#define LSEQ 4096
#define DDIM 128
#define CHUNKS 16
#define CHUNK_ROWS 256
#define STATE_SZ (DDIM*DDIM + DDIM)   // 16512 floats per (bh, chunk), [d][e] then Z[d]

typedef __attribute__((ext_vector_type(8))) short bf16x8;
typedef __attribute__((ext_vector_type(4))) float f32x4;

__device__ inline uint16_t f2bf(float f) {
    uint32_t x = __builtin_bit_cast(uint32_t, f);
    x += 0x7fffu + ((x >> 16) & 1u);
    return (uint16_t)(x >> 16);
}
__device__ inline uint32_t pack2(float a, float b) {
    return (uint32_t)f2bf(a) | ((uint32_t)f2bf(b) << 16);
}
// phi(x) = clip(elu(x*s+b)+1, 0, 10)
__device__ inline float phi_f(float x, float s, float b) {
    float y = fmaf(x, s, b);
    float pos = fminf(y + 1.0f, 10.0f);
    float neg = __expf(y);
    return (y > 0.0f) ? pos : neg;
}
// LDS-only barrier drain: keeps global prefetch loads in flight across barriers.
__device__ inline void bar_lgkm() {
    asm volatile("s_waitcnt lgkmcnt(0)\n\ts_barrier" ::: "memory");
}

// =====================================================================
// P1: per-chunk state totals  S_c = phi_K_c^T @ V_c  (K=256), Z_c
// LDS: pk bufs 2x16KB @0, vT bufs 2x16KB @32768, Zpart @65536 (2KB)
// NOTE: __launch_bounds__ second arg behaves as BLOCKS/CU here (measured:
// (512,4) capped VGPR at 64 and spilled; (512,2) gives the 128-reg budget).
#define SMEM1 67584
__global__ __launch_bounds__(512, 2) void la_state(
    const float* __restrict__ K, const float* __restrict__ V,
    const float* __restrict__ scale, const float* __restrict__ bias,
    float* __restrict__ states)
{
    extern __shared__ char smem[];
    const int tid  = threadIdx.x;
    const int bh   = blockIdx.x >> 4;
    const int ch   = blockIdx.x & 15;
    const int h    = bh & 15;
    const int lane = tid & 63;
    const int wid  = tid >> 6;
    const int i15  = lane & 15;
    const int q4   = lane >> 4;
    const size_t base = (size_t)bh * LSEQ * DDIM;
    const int row0 = ch * CHUNK_ROWS;

    const int d  = tid & 127;
    const int rg = tid >> 7;
    const float sk = scale[h*DDIM + d];
    const float bk = bias [h*DDIM + d];

    f32x4 accS[8];
    #pragma unroll
    for (int mt = 0; mt < 8; ++mt) accS[mt] = (f32x4){0.f,0.f,0.f,0.f};
    float zacc = 0.f;

    float kreg[16], vreg[16];
    auto load_kv = [&](int g) {
        const float* Kc = K + base + (size_t)(row0 + 64*g + 16*rg)*DDIM + d;
        const float* Vc = V + base + (size_t)(row0 + 64*g + 16*rg)*DDIM + d;
        #pragma unroll
        for (int j = 0; j < 16; ++j) {
            kreg[j] = Kc[(size_t)j*DDIM];
            vreg[j] = Vc[(size_t)j*DDIM];
        }
    };
    auto stage = [&](int b) {
        uint32_t wk[8], wv8[8];
        #pragma unroll
        for (int j = 0; j < 8; ++j) {
            float p0 = phi_f(kreg[2*j],   sk, bk);
            float p1 = phi_f(kreg[2*j+1], sk, bk);
            zacc += p0 + p1;
            wk[j]  = pack2(p0, p1);
            wv8[j] = pack2(vreg[2*j], vreg[2*j+1]);
        }
        char* pkb = smem + b*16384;
        char* vtb = smem + 32768 + b*16384;
        const uint32_t lin = (uint32_t)(d*128 + 32*rg);
        const uint32_t swz = (uint32_t)((d & 7) << 4);
        *(uint4*)(pkb + ((lin     ) ^ swz)) = ((const uint4*)wk)[0];
        *(uint4*)(pkb + ((lin + 16) ^ swz)) = ((const uint4*)wk)[1];
        *(uint4*)(vtb + ((lin     ) ^ swz)) = ((const uint4*)wv8)[0];
        *(uint4*)(vtb + ((lin + 16) ^ swz)) = ((const uint4*)wv8)[1];
    };

    load_kv(0);
    stage(0);
    load_kv(1);
    bar_lgkm();

    #pragma unroll
    for (int g = 0; g < 4; ++g) {
        if (g < 3) stage((g+1)&1);
        if (g < 2) load_kv(g+2);
        const char* pkb = smem + (g&1)*16384;
        const char* vtb = smem + 32768 + (g&1)*16384;
        const uint32_t swz = (uint32_t)((i15 & 7) << 4);
        #pragma unroll
        for (int ksl = 0; ksl < 2; ++ksl) {
            bf16x8 bv = *(const bf16x8*)(vtb + (((uint32_t)((16*wid+i15)*128 + 64*ksl + 16*q4)) ^ swz));
            #pragma unroll
            for (int mt = 0; mt < 8; ++mt) {
                bf16x8 av = *(const bf16x8*)(pkb + (((uint32_t)((16*mt+i15)*128 + 64*ksl + 16*q4)) ^ swz));
                accS[mt] = __builtin_amdgcn_mfma_f32_16x16x32_bf16(av, bv, accS[mt], 0, 0, 0);
            }
        }
        bar_lgkm();
    }

    float* Zpart = (float*)(smem + 65536);
    Zpart[rg*128 + d] = zacc;
    float* stb = states + (size_t)(bh*CHUNKS + ch)*STATE_SZ;
    #pragma unroll
    for (int mt = 0; mt < 8; ++mt)
        #pragma unroll
        for (int r = 0; r < 4; ++r)
            stb[(size_t)(16*mt + 4*q4 + r)*DDIM + 16*wid + i15] = accS[mt][r];
    bar_lgkm();
    if (tid < 128)
        stb[DDIM*DDIM + tid] = Zpart[tid] + Zpart[128+tid] + Zpart[256+tid] + Zpart[384+tid];
}

// =====================================================================
// Prefix: in-place exclusive prefix over the 16 chunk states, 1 chain/thread.
__global__ void la_prefix(float* __restrict__ states) {
    const int bh  = blockIdx.y;
    const int idx = blockIdx.x * 128 + threadIdx.x;   // 129*128 = 16512 exact
    float* p = states + (size_t)bh * CHUNKS * STATE_SZ + idx;
    float run = 0.f;
    #pragma unroll
    for (int c = 0; c < CHUNKS; ++c) {
        float v = p[(size_t)c * STATE_SZ];
        p[(size_t)c * STATE_SZ] = run;
        run += v;
    }
}

// =====================================================================
// P2: out = (phi_Q @ S0 + blockcausal(phi_Q @ phi_K^T) @ V) / den
// Wave w owns q-tiles a=w and a=15-w (16 rows each) -> balanced causal work.
// kv granules of 32 rows, double-buffered. 2 wg/CU (LDS 70KB, VGPR 128).
// LDS map:
//   [0,32768)       S0T [e=128][d=128] bf16 swz; A-scratch overlays after term1
//                   (per wave: wid*2560 + tile*1280, [16 q][40 r] bf16)
//   [32768,49152)   pk bufs 2 x [32 r][128 d] bf16 swz (8KB each)
//   [49152,69632)   vT bufs 2 x [128 e][40 r] bf16 pad (10KB each)
//   [69632,70656)   sbL: scale[128], bias[128] f32
//   [70656,71680)   denl [8 waves][32] f32
#define SMEM2 71680
__global__ __launch_bounds__(512, 2) void la_fwd(
    const float* __restrict__ Q, const float* __restrict__ K,
    const float* __restrict__ V, const float* __restrict__ scale,
    const float* __restrict__ bias, const float* __restrict__ states,
    float* __restrict__ out)
{
    extern __shared__ char smem[];
    char* S0T  = smem;
    char* pkB  = smem + 32768;
    char* vtB  = smem + 49152;
    float* sbL  = (float*)(smem + 69632);
    float* denl = (float*)(smem + 70656);

    const int tid  = threadIdx.x;
    const int bh   = blockIdx.x >> 4;
    const int ch   = blockIdx.x & 15;
    const int h    = bh & 15;
    const int lane = tid & 63;
    const int wid  = tid >> 6;
    const int i15  = lane & 15;
    const int q4   = lane >> 4;
    const size_t base = (size_t)bh * LSEQ * DDIM;
    const int row0 = ch * CHUNK_ROWS;
    const float* stb = states + (size_t)(bh*CHUNKS + ch)*STATE_SZ;

    // kv staging assignments (32-row granule)
    const int krow = tid >> 4;            // 0..31
    const int kc8  = (tid & 15) * 8;      // K col segment (8 wide)
    const int ve   = tid & 127;           // vT row (e)
    const int vrg  = tid >> 7;            // 0..3 -> r rows 8vrg..8vrg+7

    // q-tile ownership: balanced
    const int qa0 = wid, qa1 = 15 - wid;
    const int jmax0 = qa0 >> 1, jmax1 = qa1 >> 1;

    float4 kq[2];
    float  vr[8];
    auto load_kv = [&](int g) {
        const float* Kr = K + base + (size_t)(row0 + 32*g + krow)*DDIM + kc8;
        kq[0] = *(const float4*)(Kr);
        kq[1] = *(const float4*)(Kr + 4);
        const float* Vc = V + base + (size_t)(row0 + 32*g + 8*vrg)*DDIM + ve;
        #pragma unroll
        for (int j = 0; j < 8; ++j) vr[j] = Vc[(size_t)j*DDIM];
    };
    auto stage_kv = [&](int b) {
        float4 s0 = *(const float4*)&sbL[kc8];
        float4 s1 = *(const float4*)&sbL[kc8 + 4];
        float4 b0 = *(const float4*)&sbL[128 + kc8];
        float4 b1 = *(const float4*)&sbL[128 + kc8 + 4];
        uint32_t wk[4];
        wk[0] = pack2(phi_f(kq[0].x, s0.x, b0.x), phi_f(kq[0].y, s0.y, b0.y));
        wk[1] = pack2(phi_f(kq[0].z, s0.z, b0.z), phi_f(kq[0].w, s0.w, b0.w));
        wk[2] = pack2(phi_f(kq[1].x, s1.x, b1.x), phi_f(kq[1].y, s1.y, b1.y));
        wk[3] = pack2(phi_f(kq[1].z, s1.z, b1.z), phi_f(kq[1].w, s1.w, b1.w));
        const uint32_t lin = (uint32_t)(krow*256 + kc8*2);
        const uint32_t swz = (uint32_t)((krow & 7) << 4);
        *(uint4*)(pkB + b*8192 + (lin ^ swz)) = *(const uint4*)wk;
        uint32_t wv8[4];
        #pragma unroll
        for (int j = 0; j < 4; ++j) wv8[j] = pack2(vr[2*j], vr[2*j+1]);
        *(uint4*)(vtB + b*10240 + (uint32_t)(ve*80 + vrg*16)) = *(const uint4*)wv8;
    };

    load_kv(0);   // issue earliest

    // ---- stage scale/bias row into LDS
    if (tid < 256) sbL[tid] = (tid < 128) ? scale[h*DDIM + tid] : bias[h*DDIM + tid - 128];

    // ---- stage S0T [e][d] bf16 (2 passes of 16 d's to cap registers)
    {
        const int se  = tid & 127;
        const int sdg = tid >> 7;            // d range 32sdg..32sdg+31
        const uint32_t swz = (uint32_t)((se & 7) << 4);
        #pragma unroll
        for (int pass = 0; pass < 2; ++pass) {
            float sv[16];
            const float* sp = stb + (size_t)(32*sdg + 16*pass)*DDIM + se;
            #pragma unroll
            for (int k2 = 0; k2 < 16; ++k2) sv[k2] = sp[(size_t)k2*DDIM];
            uint32_t wbuf[8];
            #pragma unroll
            for (int k2 = 0; k2 < 8; ++k2) wbuf[k2] = pack2(sv[2*k2], sv[2*k2+1]);
            const uint32_t linb = (uint32_t)(se*256 + (32*sdg + 16*pass)*2);
            *(uint4*)(S0T + ((linb     ) ^ swz)) = ((const uint4*)wbuf)[0];
            *(uint4*)(S0T + ((linb + 16) ^ swz)) = ((const uint4*)wbuf)[1];
        }
    }

    // ---- phi_Q fragments in registers + den0 = phi_q . Z0
    bf16x8 pq[2][4];
    float dden0 = 0.f, dden1 = 0.f;
    #pragma unroll
    for (int ks = 0; ks < 4; ++ks) {
        const float* sp = scale + h*DDIM + 32*ks + 8*q4;
        const float* bp = bias  + h*DDIM + 32*ks + 8*q4;
        const float* zp = stb + DDIM*DDIM + 32*ks + 8*q4;
        float4 s0 = *(const float4*)sp, s1 = *(const float4*)(sp+4);
        float4 b0 = *(const float4*)bp, b1 = *(const float4*)(bp+4);
        float4 z0 = *(const float4*)zp, z1 = *(const float4*)(zp+4);
        #pragma unroll
        for (int tl = 0; tl < 2; ++tl) {
            const int a = tl ? qa1 : qa0;
            const float* qp = Q + base + (size_t)(row0 + 16*a + i15)*DDIM + 32*ks + 8*q4;
            float4 a0 = *(const float4*)qp, a1 = *(const float4*)(qp+4);
            float f0 = phi_f(a0.x, s0.x, b0.x), f1 = phi_f(a0.y, s0.y, b0.y);
            float f2 = phi_f(a0.z, s0.z, b0.z), f3 = phi_f(a0.w, s0.w, b0.w);
            float f4 = phi_f(a1.x, s1.x, b1.x), f5 = phi_f(a1.y, s1.y, b1.y);
            float f6 = phi_f(a1.z, s1.z, b1.z), f7 = phi_f(a1.w, s1.w, b1.w);
            float ds = f0*z0.x + f1*z0.y + f2*z0.z + f3*z0.w
                     + f4*z1.x + f5*z1.y + f6*z1.z + f7*z1.w;
            if (tl == 0) dden0 += ds; else dden1 += ds;
            uint4 uu = { pack2(f0,f1), pack2(f2,f3), pack2(f4,f5), pack2(f6,f7) };
            pq[tl][ks] = __builtin_bit_cast(bf16x8, uu);
        }
    }

    stage_kv(0);
    load_kv(1);
    bar_lgkm();   // B0: S0T + sbL + kv g0 visible

    // ---- term1: acc = phi_q @ S0
    f32x4 acc[2][8];
    #pragma unroll
    for (int tl = 0; tl < 2; ++tl)
        #pragma unroll
        for (int et = 0; et < 8; ++et) acc[tl][et] = (f32x4){0.f,0.f,0.f,0.f};
    {
        const uint32_t swz = (uint32_t)((i15 & 7) << 4);
        #pragma unroll
        for (int ks = 0; ks < 4; ++ks)
            #pragma unroll
            for (int et = 0; et < 8; ++et) {
                bf16x8 sb = *(const bf16x8*)(S0T + (((uint32_t)((16*et+i15)*256 + (32*ks + 8*q4)*2)) ^ swz));
                acc[0][et] = __builtin_amdgcn_mfma_f32_16x16x32_bf16(pq[0][ks], sb, acc[0][et], 0, 0, 0);
                acc[1][et] = __builtin_amdgcn_mfma_f32_16x16x32_bf16(pq[1][ks], sb, acc[1][et], 0, 0, 0);
            }
    }
    stage_kv(1);
    load_kv(2);
    bar_lgkm();   // B1: all term1 S0T reads done -> A-scratch may overwrite; kv g1 visible

    // ---- kv loop: 8 granules of 32 rows, double-buffered
    char* Ascr0 = S0T + wid*2560;
    char* Ascr1 = Ascr0 + 1280;
    const uint32_t swzf = (uint32_t)((i15 & 7) << 4);

    #pragma unroll
    for (int t = 0; t < 8; ++t) {
        if (t >= 1) {
            if (t + 1 <= 7) stage_kv((t+1)&1);
            if (t + 2 <= 7) load_kv(t+2);
        }
        const char* pk = pkB + (t&1)*8192;
        const char* vt = vtB + (t&1)*10240;
        #pragma unroll
        for (int tl = 0; tl < 2; ++tl) {
            const int jm = tl ? jmax1 : jmax0;
            if (t <= jm) {
                char* As = tl ? Ascr1 : Ascr0;
                f32x4 Aacc[2];
                Aacc[0] = (f32x4){0.f,0.f,0.f,0.f};
                Aacc[1] = (f32x4){0.f,0.f,0.f,0.f};
                #pragma unroll
                for (int ks = 0; ks < 4; ++ks) {
                    bf16x8 ak0 = *(const bf16x8*)(pk + (((uint32_t)((     i15)*256 + (32*ks + 8*q4)*2)) ^ swzf));
                    bf16x8 ak1 = *(const bf16x8*)(pk + (((uint32_t)((16 + i15)*256 + (32*ks + 8*q4)*2)) ^ swzf));
                    bf16x8 pqv = tl ? pq[1][ks] : pq[0][ks];
                    Aacc[0] = __builtin_amdgcn_mfma_f32_16x16x32_bf16(ak0, pqv, Aacc[0], 0, 0, 0);
                    Aacc[1] = __builtin_amdgcn_mfma_f32_16x16x32_bf16(ak1, pqv, Aacc[1], 0, 0, 0);
                }
                float dsum = Aacc[0][0]+Aacc[0][1]+Aacc[0][2]+Aacc[0][3]
                           + Aacc[1][0]+Aacc[1][1]+Aacc[1][2]+Aacc[1][3];
                if (tl == 0) dden0 += dsum; else dden1 += dsum;
                #pragma unroll
                for (int sub = 0; sub < 2; ++sub) {
                    uint2 o;
                    o.x = pack2(Aacc[sub][0], Aacc[sub][1]);
                    o.y = pack2(Aacc[sub][2], Aacc[sub][3]);
                    *(uint2*)(As + (uint32_t)((i15*40 + 16*sub + 4*q4)*2)) = o;
                }
                bf16x8 aq = *(const bf16x8*)(As + (uint32_t)((i15*40 + 8*q4)*2));
                #pragma unroll
                for (int et = 0; et < 8; ++et) {
                    bf16x8 bv = *(const bf16x8*)(vt + (uint32_t)((16*et+i15)*80 + q4*16));
                    acc[tl][et] = __builtin_amdgcn_mfma_f32_16x16x32_bf16(aq, bv, acc[tl][et], 0, 0, 0);
                }
            }
        }
        bar_lgkm();
    }

    // ---- den reduce (per wave, via shuffle + wave-private LDS) + store
    dden0 += __shfl_xor(dden0, 16, 64); dden0 += __shfl_xor(dden0, 32, 64);
    dden1 += __shfl_xor(dden1, 16, 64); dden1 += __shfl_xor(dden1, 32, 64);
    if (q4 == 0) {
        denl[wid*32 + i15]      = dden0;
        denl[wid*32 + 16 + i15] = dden1;
    }
    #pragma unroll
    for (int tl = 0; tl < 2; ++tl) {
        const int a = tl ? qa1 : qa0;
        float inv[4];
        #pragma unroll
        for (int r = 0; r < 4; ++r)
            inv[r] = 1.0f / fmaxf(denl[wid*32 + 16*tl + 4*q4 + r], 1e-6f);
        #pragma unroll
        for (int et = 0; et < 8; ++et)
            #pragma unroll
            for (int r = 0; r < 4; ++r)
                out[base + (size_t)(row0 + 16*a + 4*q4 + r)*DDIM + 16*et + i15] =
                    acc[tl][et][r] * inv[r];
    }
}

extern "C" void kernel_launch(void* const* d_in, const int* in_sizes, int n_in,
                              void* d_out, int out_size, void* d_ws, size_t ws_size,
                              hipStream_t stream) {
    const float* Q     = (const float*)d_in[0];
    const float* K     = (const float*)d_in[1];
    const float* V     = (const float*)d_in[2];
    const float* scale = (const float*)d_in[3];
    const float* bias  = (const float*)d_in[4];
    float* out    = (float*)d_out;
    float* states = (float*)d_ws;   // 32*16*16512*4 = 33.8 MB

    static bool s_attr = false;
    if (!s_attr) {
        hipFuncSetAttribute(reinterpret_cast<const void*>(la_state),
                            hipFuncAttributeMaxDynamicSharedMemorySize, SMEM1);
        hipFuncSetAttribute(reinterpret_cast<const void*>(la_fwd),
                            hipFuncAttributeMaxDynamicSharedMemorySize, SMEM2);
        s_attr = true;
    }

    hipLaunchKernelGGL(la_state, dim3(BH*CHUNKS), dim3(512), SMEM1, stream,
                       K, V, scale, bias, states);
    hipLaunchKernelGGL(la_prefix, dim3(129, BH), dim3(128), 0, stream, states);
    hipLaunchKernelGGL(la_fwd, dim3(BH*CHUNKS), dim3(512), SMEM2, stream,
                       Q, K, V, scale, bias, states, out);
}